// Round 1
// baseline (540.119 us; speedup 1.0000x reference)
//
#include <hip/hip_runtime.h>
#include <hip/hip_bf16.h>
#include <type_traits>

#define B_ 8
#define L_ 8192
#define D_ 512
#define H_ 8
#define KD_ 64
#define W_ 128
#define C_ 64
#define M_ (B_ * L_)   // 65536
#define HK_ 512

typedef __bf16 bf16_t;
typedef __bf16 bf16x8 __attribute__((ext_vector_type(8)));
typedef float f32x4 __attribute__((ext_vector_type(4)));

// ---------------------------------------------------------------------------
// Prep: wt[mat][n][d] = W[mat][d][n]  (bf16, transposed, q-scale folded)
// ---------------------------------------------------------------------------
__global__ void prep_weights_kernel(const float* __restrict__ Wq,
                                    const float* __restrict__ Wk,
                                    const float* __restrict__ Wv,
                                    const float* __restrict__ Wo,
                                    bf16_t* __restrict__ wt) {
  const int n = blockIdx.x;    // 0..511 (output row of W^T)
  const int mat = blockIdx.y;  // 0..3
  const float* src = (mat == 0) ? Wq : (mat == 1) ? Wk : (mat == 2) ? Wv : Wo;
  const float scale = (mat == 0) ? 0.125f : 1.0f;  // 1/sqrt(64) folded into Wq
  bf16_t* dst = wt + ((size_t)mat * 512 + n) * 512;
  for (int d = threadIdx.x; d < 512; d += blockDim.x) {
    dst[d] = (bf16_t)(src[(size_t)d * 512 + n] * scale);
  }
}

// ---------------------------------------------------------------------------
// GEMM: C[m][n] = sum_k A[m][k] * BT[n][k]
//   A: fp32 (converted inline) or bf16;  BT: bf16 [Ntot][Kdim];  C: bf16 or f32
//   BM=BN=128, BK=64, 256 threads (4 waves, 2x2 of 64x64).
//   If n0 >= Ndim, output goes to C2 at column n0-Ndim (fused K/V launch).
// ---------------------------------------------------------------------------
template <typename AT, typename OT>
__global__ __launch_bounds__(256, 2)
void gemm_bt(const AT* __restrict__ A, const bf16_t* __restrict__ BT,
             OT* __restrict__ Cmat, OT* __restrict__ C2,
             int Mdim, int Ndim, int Kdim) {
  __shared__ bf16_t sA[128][72];  // +8 pad: conflict-free, 16B-aligned rows
  __shared__ bf16_t sB[128][72];

  const int tid = threadIdx.x;
  const int lane = tid & 63;
  const int w = tid >> 6;
  const int wr = (w >> 1) * 64;
  const int wc = (w & 1) * 64;
  const int m0 = blockIdx.y * 128;
  const int n0 = blockIdx.x * 128;

  const bool second = (n0 >= Ndim);
  OT* const outp = second ? C2 : Cmat;
  const int n0o = second ? (n0 - Ndim) : n0;

  const int r = tid >> 1;             // 0..127 staging row
  const int cpart = (tid & 1) * 32;   // col half

  f32x4 acc[4][4] = {};

  for (int k0 = 0; k0 < Kdim; k0 += 64) {
    // ---- stage A tile [128][64] ----
    if constexpr (std::is_same<AT, float>::value) {
      const float* ap = A + (size_t)(m0 + r) * Kdim + k0 + cpart;
      float4 f[8];
#pragma unroll
      for (int i = 0; i < 8; i++) f[i] = *reinterpret_cast<const float4*>(ap + i * 4);
#pragma unroll
      for (int i = 0; i < 8; i++) {
        bf16_t* d = &sA[r][cpart + i * 4];
        d[0] = (bf16_t)f[i].x; d[1] = (bf16_t)f[i].y;
        d[2] = (bf16_t)f[i].z; d[3] = (bf16_t)f[i].w;
      }
    } else {
      const bf16_t* ap = A + (size_t)(m0 + r) * Kdim + k0 + cpart;
#pragma unroll
      for (int i = 0; i < 4; i++)
        *reinterpret_cast<int4*>(&sA[r][cpart + i * 8]) =
            *reinterpret_cast<const int4*>(ap + i * 8);
    }
    // ---- stage B tile [128][64] (BT already transposed bf16) ----
    {
      const bf16_t* bp = BT + (size_t)(n0 + r) * Kdim + k0 + cpart;
#pragma unroll
      for (int i = 0; i < 4; i++)
        *reinterpret_cast<int4*>(&sB[r][cpart + i * 8]) =
            *reinterpret_cast<const int4*>(bp + i * 8);
    }
    __syncthreads();

    const int cl = lane & 15;
    const int g = lane >> 4;
#pragma unroll
    for (int kk = 0; kk < 2; kk++) {
      bf16x8 afr[4], bfr[4];
#pragma unroll
      for (int t = 0; t < 4; t++)
        afr[t] = *reinterpret_cast<const bf16x8*>(&sA[wr + t * 16 + cl][kk * 32 + g * 8]);
#pragma unroll
      for (int t = 0; t < 4; t++)
        bfr[t] = *reinterpret_cast<const bf16x8*>(&sB[wc + t * 16 + cl][kk * 32 + g * 8]);
#pragma unroll
      for (int i = 0; i < 4; i++)
#pragma unroll
        for (int j = 0; j < 4; j++)
          acc[i][j] = __builtin_amdgcn_mfma_f32_16x16x32_bf16(afr[i], bfr[j], acc[i][j], 0, 0, 0);
    }
    __syncthreads();
  }

  // ---- epilogue: C/D layout col=lane&15, row=(lane>>4)*4+jj ----
  const int crow = (lane >> 4) * 4;
  const int ccol = lane & 15;
#pragma unroll
  for (int i = 0; i < 4; i++) {
#pragma unroll
    for (int j = 0; j < 4; j++) {
      const int gm = m0 + wr + i * 16 + crow;
      const int gn = n0o + wc + j * 16 + ccol;
#pragma unroll
      for (int jj = 0; jj < 4; jj++) {
        const float vv = acc[i][j][jj];
        if constexpr (std::is_same<OT, float>::value)
          outp[(size_t)(gm + jj) * Ndim + gn] = vv;
        else
          outp[(size_t)(gm + jj) * Ndim + gn] = (bf16_t)vv;
      }
    }
  }
}

// ---------------------------------------------------------------------------
// Attention: one block per (h, c, b). 4 waves x 32 rows. W=128 queries,
// 128 chunk keys via MFMA + CLS key handled separately (VALU dot + rank-1).
// ---------------------------------------------------------------------------
__global__ __launch_bounds__(256, 2)
void attn_kernel(const bf16_t* __restrict__ q, const bf16_t* __restrict__ k,
                 const bf16_t* __restrict__ v, bf16_t* __restrict__ ctx) {
  const int h = blockIdx.x;
  const int c = blockIdx.y;
  const int b = blockIdx.z;
  const int tid = threadIdx.x;
  const int lane = tid & 63;
  const int w = tid >> 6;
  const int cl = lane & 15;
  const int g = lane >> 4;

  __shared__ bf16_t vT[64][136];    // V^T: [kdim][m]
  __shared__ bf16_t pL[128][136];   // normalized P (bf16)
  __shared__ float scls[128];       // cls scores per row
  __shared__ float pclsn[128];      // normalized cls prob per row
  __shared__ float kcls[64];
  __shared__ float vcls[64];

  const size_t headoff = (size_t)h * KD_;
  const size_t rowbase = (size_t)b * L_ + (size_t)c * W_;

  // stage cls K/V (global position 0 of this batch)
  if (tid < 64) {
    kcls[tid] = (float)k[(size_t)b * L_ * HK_ + headoff + tid];
    vcls[tid] = (float)v[(size_t)b * L_ * HK_ + headoff + tid];
  }
  // stage V^T
  {
    const int m = tid >> 1;
    const int kd0 = (tid & 1) * 32;
    const bf16_t* vp = v + (rowbase + m) * HK_ + headoff + kd0;
#pragma unroll
    for (int i = 0; i < 4; i++) {
      bf16x8 t8 = *reinterpret_cast<const bf16x8*>(vp + i * 8);
#pragma unroll
      for (int j = 0; j < 8; j++) vT[kd0 + i * 8 + j][m] = t8[j];
    }
  }

  // Q fragments (direct from global)
  bf16x8 qf[2][2];
#pragma unroll
  for (int rt = 0; rt < 2; rt++)
#pragma unroll
    for (int kk = 0; kk < 2; kk++) {
      const size_t row = rowbase + w * 32 + rt * 16 + cl;
      qf[rt][kk] = *reinterpret_cast<const bf16x8*>(&q[row * HK_ + headoff + kk * 32 + g * 8]);
    }

  // QK^T: scores[128 rows x 128 chunk keys], this wave: rows w*32..+32
  f32x4 sacc[2][8] = {};
#pragma unroll
  for (int ct = 0; ct < 8; ct++) {
    bf16x8 kf[2];
#pragma unroll
    for (int kk = 0; kk < 2; kk++) {
      const size_t rowm = rowbase + ct * 16 + cl;
      kf[kk] = *reinterpret_cast<const bf16x8*>(&k[rowm * HK_ + headoff + kk * 32 + g * 8]);
    }
#pragma unroll
    for (int rt = 0; rt < 2; rt++)
#pragma unroll
      for (int kk = 0; kk < 2; kk++)
        sacc[rt][ct] = __builtin_amdgcn_mfma_f32_16x16x32_bf16(qf[rt][kk], kf[kk], sacc[rt][ct], 0, 0, 0);
  }

  __syncthreads();  // kcls/vcls/vT staged

  // CLS scores (VALU): row = w*32 + rt*16 + cl
#pragma unroll
  for (int rt = 0; rt < 2; rt++) {
    float part = 0.f;
#pragma unroll
    for (int kk = 0; kk < 2; kk++)
#pragma unroll
      for (int j = 0; j < 8; j++)
        part += (float)qf[rt][kk][j] * kcls[kk * 32 + g * 8 + j];
    part += __shfl_xor(part, 16);
    part += __shfl_xor(part, 32);
    if (g == 0) scls[w * 32 + rt * 16 + cl] = part;
  }

  // softmax (rows live at: row = w*32 + rt*16 + g*4 + jj, cols spread over
  // lanes cl=0..15 within each 16-lane group, plus in-lane ct dimension)
  float invd[2][4];
#pragma unroll
  for (int rt = 0; rt < 2; rt++) {
#pragma unroll
    for (int jj = 0; jj < 4; jj++) {
      float mx = sacc[rt][0][jj];
#pragma unroll
      for (int ct = 1; ct < 8; ct++) mx = fmaxf(mx, sacc[rt][ct][jj]);
#pragma unroll
      for (int d = 1; d < 16; d <<= 1) mx = fmaxf(mx, __shfl_xor(mx, d));
      const float sc = scls[w * 32 + rt * 16 + g * 4 + jj];
      mx = fmaxf(mx, sc);
      float sum = 0.f;
#pragma unroll
      for (int ct = 0; ct < 8; ct++) {
        const float e = __expf(sacc[rt][ct][jj] - mx);
        sacc[rt][ct][jj] = e;
        sum += e;
      }
#pragma unroll
      for (int d = 1; d < 16; d <<= 1) sum += __shfl_xor(sum, d);
      const float pc = __expf(sc - mx);
      sum += pc;
      const float inv = 1.0f / sum;
      invd[rt][jj] = inv;
      if (cl == 0) pclsn[w * 32 + rt * 16 + g * 4 + jj] = pc * inv;
    }
  }

  // write normalized P (bf16) for PV MFMA A-operand
#pragma unroll
  for (int rt = 0; rt < 2; rt++)
#pragma unroll
    for (int jj = 0; jj < 4; jj++) {
      const int row = w * 32 + rt * 16 + g * 4 + jj;
#pragma unroll
      for (int ct = 0; ct < 8; ct++)
        pL[row][ct * 16 + cl] = (bf16_t)(sacc[rt][ct][jj] * invd[rt][jj]);
    }
  __syncthreads();

  // PV: ctx[128 x 64] = P[128 x 128] @ V[128 x 64]
  f32x4 cacc[2][4] = {};
#pragma unroll
  for (int kk = 0; kk < 4; kk++) {  // m-dimension, 4 x 32
    bf16x8 vf[4];
#pragma unroll
    for (int c2 = 0; c2 < 4; c2++)
      vf[c2] = *reinterpret_cast<const bf16x8*>(&vT[c2 * 16 + cl][kk * 32 + g * 8]);
#pragma unroll
    for (int rt = 0; rt < 2; rt++) {
      const bf16x8 pf = *reinterpret_cast<const bf16x8*>(&pL[w * 32 + rt * 16 + cl][kk * 32 + g * 8]);
#pragma unroll
      for (int c2 = 0; c2 < 4; c2++)
        cacc[rt][c2] = __builtin_amdgcn_mfma_f32_16x16x32_bf16(pf, vf[c2], cacc[rt][c2], 0, 0, 0);
    }
  }

  // epilogue: add CLS rank-1 term, store bf16 ctx
#pragma unroll
  for (int rt = 0; rt < 2; rt++)
#pragma unroll
    for (int c2 = 0; c2 < 4; c2++)
#pragma unroll
      for (int jj = 0; jj < 4; jj++) {
        const int row = w * 32 + rt * 16 + g * 4 + jj;
        const int kd = c2 * 16 + cl;
        const float val = cacc[rt][c2][jj] + pclsn[row] * vcls[kd];
        ctx[(rowbase + row) * HK_ + headoff + kd] = (bf16_t)val;
      }
}

// ---------------------------------------------------------------------------
extern "C" void kernel_launch(void* const* d_in, const int* in_sizes, int n_in,
                              void* d_out, int out_size, void* d_ws, size_t ws_size,
                              hipStream_t stream) {
  const float* Xq = (const float*)d_in[0];
  const float* Xkv = (const float*)d_in[1];
  const float* Wq = (const float*)d_in[2];
  const float* Wk = (const float*)d_in[3];
  const float* Wv = (const float*)d_in[4];
  const float* Wo = (const float*)d_in[5];
  float* out = (float*)d_out;

  char* ws = (char*)d_ws;
  bf16_t* wT = (bf16_t*)ws;                                  // 4 x 512 x 512 bf16
  size_t off = (size_t)4 * 512 * 512 * sizeof(bf16_t);       // 2 MiB
  bf16_t* qb = (bf16_t*)(ws + off); off += (size_t)M_ * HK_ * 2;
  bf16_t* kb = (bf16_t*)(ws + off); off += (size_t)M_ * HK_ * 2;
  bf16_t* vb = (bf16_t*)(ws + off); off += (size_t)M_ * HK_ * 2;
  bf16_t* ctxb = (bf16_t*)(ws + off);

  bf16_t* wTq = wT;
  bf16_t* wTk = wT + (size_t)512 * 512;      // wTk,wTv contiguous (1024 rows)
  bf16_t* wTo = wT + (size_t)3 * 512 * 512;

  prep_weights_kernel<<<dim3(512, 4), 128, 0, stream>>>(Wq, Wk, Wv, Wo, wT);

  // Q projection (scale folded into wTq)
  gemm_bt<float, bf16_t><<<dim3(4, M_ / 128), 256, 0, stream>>>(
      Xq, wTq, qb, qb, M_, HK_, D_);
  // K+V projections fused (shared Xkv staging): BT has 1024 rows
  gemm_bt<float, bf16_t><<<dim3(8, M_ / 128), 256, 0, stream>>>(
      Xkv, wTk, kb, vb, M_, HK_, D_);

  attn_kernel<<<dim3(H_, C_, B_), 256, 0, stream>>>(qb, kb, vb, ctxb);

  // Output projection: ctx [M][512] bf16 @ WoT -> out fp32
  gemm_bt<bf16_t, float><<<dim3(4, M_ / 128), 256, 0, stream>>>(
      ctxb, wTo, out, out, M_, D_, HK_);
}

// Round 2
// 421.995 us; speedup vs baseline: 1.2799x; 1.2799x over previous
//
#include <hip/hip_runtime.h>
#include <hip/hip_bf16.h>
#include <type_traits>

#define B_ 8
#define L_ 8192
#define D_ 512
#define H_ 8
#define KD_ 64
#define W_ 128
#define C_ 64
#define M_ (B_ * L_)   // 65536
#define HK_ 512

typedef __bf16 bf16_t;
typedef __bf16 bf16x8 __attribute__((ext_vector_type(8)));
typedef float f32x4 __attribute__((ext_vector_type(4)));

#define GLOAD16(gp, lp)                                                        \
  __builtin_amdgcn_global_load_lds(                                            \
      (const __attribute__((address_space(1))) unsigned int*)(gp),             \
      (__attribute__((address_space(3))) unsigned int*)(lp), 16, 0, 0)

// ---------------------------------------------------------------------------
// Prep: wt[mat][n][d] = W[mat][d][n]  (bf16, transposed, q-scale folded)
// ---------------------------------------------------------------------------
__global__ void prep_weights_kernel(const float* __restrict__ Wq,
                                    const float* __restrict__ Wk,
                                    const float* __restrict__ Wv,
                                    const float* __restrict__ Wo,
                                    bf16_t* __restrict__ wt) {
  const int n = blockIdx.x;    // 0..511 (output row of W^T)
  const int mat = blockIdx.y;  // 0..3
  const float* src = (mat == 0) ? Wq : (mat == 1) ? Wk : (mat == 2) ? Wv : Wo;
  const float scale = (mat == 0) ? 0.125f : 1.0f;  // 1/sqrt(64) folded into Wq
  bf16_t* dst = wt + ((size_t)mat * 512 + n) * 512;
  for (int d = threadIdx.x; d < 512; d += blockDim.x) {
    dst[d] = (bf16_t)(src[(size_t)d * 512 + n] * scale);
  }
}

// ---------------------------------------------------------------------------
// Convert Xq / Xkv fp32 -> bf16 (streaming, vectorized 8 elem/thread)
// ---------------------------------------------------------------------------
__global__ void cvt_x_kernel(const float* __restrict__ xq,
                             const float* __restrict__ xkv,
                             bf16_t* __restrict__ oq,
                             bf16_t* __restrict__ okv) {
  const float* src = blockIdx.y ? xkv : xq;
  bf16_t* dst = blockIdx.y ? okv : oq;
  const size_t e = ((size_t)blockIdx.x * blockDim.x + threadIdx.x) * 8;
  float4 a = *reinterpret_cast<const float4*>(src + e);
  float4 b = *reinterpret_cast<const float4*>(src + e + 4);
  bf16x8 o;
  o[0] = (bf16_t)a.x; o[1] = (bf16_t)a.y; o[2] = (bf16_t)a.z; o[3] = (bf16_t)a.w;
  o[4] = (bf16_t)b.x; o[5] = (bf16_t)b.y; o[6] = (bf16_t)b.z; o[7] = (bf16_t)b.w;
  *reinterpret_cast<bf16x8*>(dst + e) = o;
}

// ---------------------------------------------------------------------------
// GEMM (m97 structure): C[m][n] = sum_k A[m][k] * BT[n][k], all-bf16 inputs.
//   BM=BN=128, BK=64, 256 threads (4 waves, 2x2 of 64x64), linear LDS tiles,
//   global_load_lds width-16 staging. Kdim fixed = 512.
//   If n0 >= Ndim, output goes to C2 at column n0-Ndim (fused K/V launch).
// ---------------------------------------------------------------------------
template <typename OT>
__global__ __launch_bounds__(256, 2)
void gemm_bt16(const bf16_t* __restrict__ A, const bf16_t* __restrict__ BT,
               OT* __restrict__ Cmat, OT* __restrict__ C2, int Ndim) {
  __shared__ bf16_t sA[128 * 64];
  __shared__ bf16_t sB[128 * 64];

  const int tid = threadIdx.x;
  const int lane = tid & 63;
  const int w = tid >> 6;
  const int wr = (w >> 1) * 64;
  const int wc = (w & 1) * 64;
  const int m0 = blockIdx.y * 128;
  const int n0 = blockIdx.x * 128;

  const bool second = (n0 >= Ndim);
  OT* const outp = second ? C2 : Cmat;
  const int n0o = second ? (n0 - Ndim) : n0;

  const int srow = tid >> 3;       // 0..31 staging row within a 32-row issue
  const int scol = (tid & 7) * 8;  // bf16 col (16B per lane)
  const int cl = lane & 15;
  const int g = lane >> 4;
  const int Kdim = 512;

  f32x4 acc[4][4] = {};

  for (int k0 = 0; k0 < Kdim; k0 += 64) {
    // ---- async stage A and B tiles [128][64] via global_load_lds x16B ----
#pragma unroll
    for (int i = 0; i < 4; i++) {
      const bf16_t* gp = A + (size_t)(m0 + i * 32 + srow) * Kdim + k0 + scol;
      char* lp = (char*)sA + i * 4096 + w * 1024;  // wave-uniform dest
      GLOAD16(gp, lp);
    }
#pragma unroll
    for (int i = 0; i < 4; i++) {
      const bf16_t* gp = BT + (size_t)(n0 + i * 32 + srow) * Kdim + k0 + scol;
      char* lp = (char*)sB + i * 4096 + w * 1024;
      GLOAD16(gp, lp);
    }
    __syncthreads();  // vmcnt(0) drain + barrier

#pragma unroll
    for (int kk = 0; kk < 2; kk++) {
      bf16x8 afr[4], bfr[4];
#pragma unroll
      for (int t = 0; t < 4; t++)
        afr[t] = *reinterpret_cast<const bf16x8*>(
            &sA[(wr + t * 16 + cl) * 64 + kk * 32 + g * 8]);
#pragma unroll
      for (int t = 0; t < 4; t++)
        bfr[t] = *reinterpret_cast<const bf16x8*>(
            &sB[(wc + t * 16 + cl) * 64 + kk * 32 + g * 8]);
#pragma unroll
      for (int i = 0; i < 4; i++)
#pragma unroll
        for (int j = 0; j < 4; j++)
          acc[i][j] = __builtin_amdgcn_mfma_f32_16x16x32_bf16(afr[i], bfr[j],
                                                              acc[i][j], 0, 0, 0);
    }
    __syncthreads();
  }

  // ---- epilogue: C/D layout col=lane&15, row=(lane>>4)*4+jj ----
  const int crow = (lane >> 4) * 4;
  const int ccol = lane & 15;
#pragma unroll
  for (int i = 0; i < 4; i++) {
#pragma unroll
    for (int j = 0; j < 4; j++) {
      const int gm = m0 + wr + i * 16 + crow;
      const int gn = n0o + wc + j * 16 + ccol;
#pragma unroll
      for (int jj = 0; jj < 4; jj++) {
        const float vv = acc[i][j][jj];
        if constexpr (std::is_same<OT, float>::value)
          outp[(size_t)(gm + jj) * Ndim + gn] = vv;
        else
          outp[(size_t)(gm + jj) * Ndim + gn] = (bf16_t)vv;
      }
    }
  }
}

// ---------------------------------------------------------------------------
// Attention: one block per (h, c, b). 4 waves x 32 rows. W=128 queries,
// 128 chunk keys via MFMA + CLS key handled separately (VALU dot + rank-1).
// ---------------------------------------------------------------------------
__global__ __launch_bounds__(256, 2)
void attn_kernel(const bf16_t* __restrict__ q, const bf16_t* __restrict__ k,
                 const bf16_t* __restrict__ v, bf16_t* __restrict__ ctx) {
  const int h = blockIdx.x;
  const int c = blockIdx.y;
  const int b = blockIdx.z;
  const int tid = threadIdx.x;
  const int lane = tid & 63;
  const int w = tid >> 6;
  const int cl = lane & 15;
  const int g = lane >> 4;

  __shared__ bf16_t vT[64][136];    // V^T: [kdim][m]
  __shared__ bf16_t pL[128][136];   // normalized P (bf16)
  __shared__ float scls[128];       // cls scores per row
  __shared__ float pclsn[128];      // normalized cls prob per row
  __shared__ float kcls[64];
  __shared__ float vcls[64];

  const size_t headoff = (size_t)h * KD_;
  const size_t rowbase = (size_t)b * L_ + (size_t)c * W_;

  // stage cls K/V (global position 0 of this batch)
  if (tid < 64) {
    kcls[tid] = (float)k[(size_t)b * L_ * HK_ + headoff + tid];
    vcls[tid] = (float)v[(size_t)b * L_ * HK_ + headoff + tid];
  }
  // stage V^T
  {
    const int m = tid >> 1;
    const int kd0 = (tid & 1) * 32;
    const bf16_t* vp = v + (rowbase + m) * HK_ + headoff + kd0;
#pragma unroll
    for (int i = 0; i < 4; i++) {
      bf16x8 t8 = *reinterpret_cast<const bf16x8*>(vp + i * 8);
#pragma unroll
      for (int j = 0; j < 8; j++) vT[kd0 + i * 8 + j][m] = t8[j];
    }
  }

  // Q fragments (direct from global)
  bf16x8 qf[2][2];
#pragma unroll
  for (int rt = 0; rt < 2; rt++)
#pragma unroll
    for (int kk = 0; kk < 2; kk++) {
      const size_t row = rowbase + w * 32 + rt * 16 + cl;
      qf[rt][kk] = *reinterpret_cast<const bf16x8*>(&q[row * HK_ + headoff + kk * 32 + g * 8]);
    }

  // QK^T: scores[128 rows x 128 chunk keys], this wave: rows w*32..+32
  f32x4 sacc[2][8] = {};
#pragma unroll
  for (int ct = 0; ct < 8; ct++) {
    bf16x8 kf[2];
#pragma unroll
    for (int kk = 0; kk < 2; kk++) {
      const size_t rowm = rowbase + ct * 16 + cl;
      kf[kk] = *reinterpret_cast<const bf16x8*>(&k[rowm * HK_ + headoff + kk * 32 + g * 8]);
    }
#pragma unroll
    for (int rt = 0; rt < 2; rt++)
#pragma unroll
      for (int kk = 0; kk < 2; kk++)
        sacc[rt][ct] = __builtin_amdgcn_mfma_f32_16x16x32_bf16(qf[rt][kk], kf[kk], sacc[rt][ct], 0, 0, 0);
  }

  __syncthreads();  // kcls/vcls/vT staged

  // CLS scores (VALU): row = w*32 + rt*16 + cl
#pragma unroll
  for (int rt = 0; rt < 2; rt++) {
    float part = 0.f;
#pragma unroll
    for (int kk = 0; kk < 2; kk++)
#pragma unroll
      for (int j = 0; j < 8; j++)
        part += (float)qf[rt][kk][j] * kcls[kk * 32 + g * 8 + j];
    part += __shfl_xor(part, 16);
    part += __shfl_xor(part, 32);
    if (g == 0) scls[w * 32 + rt * 16 + cl] = part;
  }

  // softmax (rows live at: row = w*32 + rt*16 + g*4 + jj, cols spread over
  // lanes cl=0..15 within each 16-lane group, plus in-lane ct dimension)
  float invd[2][4];
#pragma unroll
  for (int rt = 0; rt < 2; rt++) {
#pragma unroll
    for (int jj = 0; jj < 4; jj++) {
      float mx = sacc[rt][0][jj];
#pragma unroll
      for (int ct = 1; ct < 8; ct++) mx = fmaxf(mx, sacc[rt][ct][jj]);
#pragma unroll
      for (int d = 1; d < 16; d <<= 1) mx = fmaxf(mx, __shfl_xor(mx, d));
      const float sc = scls[w * 32 + rt * 16 + g * 4 + jj];
      mx = fmaxf(mx, sc);
      float sum = 0.f;
#pragma unroll
      for (int ct = 0; ct < 8; ct++) {
        const float e = __expf(sacc[rt][ct][jj] - mx);
        sacc[rt][ct][jj] = e;
        sum += e;
      }
#pragma unroll
      for (int d = 1; d < 16; d <<= 1) sum += __shfl_xor(sum, d);
      const float pc = __expf(sc - mx);
      sum += pc;
      const float inv = 1.0f / sum;
      invd[rt][jj] = inv;
      if (cl == 0) pclsn[w * 32 + rt * 16 + g * 4 + jj] = pc * inv;
    }
  }

  // write normalized P (bf16) for PV MFMA A-operand
#pragma unroll
  for (int rt = 0; rt < 2; rt++)
#pragma unroll
    for (int jj = 0; jj < 4; jj++) {
      const int row = w * 32 + rt * 16 + g * 4 + jj;
#pragma unroll
      for (int ct = 0; ct < 8; ct++)
        pL[row][ct * 16 + cl] = (bf16_t)(sacc[rt][ct][jj] * invd[rt][jj]);
    }
  __syncthreads();

  // PV: ctx[128 x 64] = P[128 x 128] @ V[128 x 64]
  f32x4 cacc[2][4] = {};
#pragma unroll
  for (int kk = 0; kk < 4; kk++) {  // m-dimension, 4 x 32
    bf16x8 vf[4];
#pragma unroll
    for (int c2 = 0; c2 < 4; c2++)
      vf[c2] = *reinterpret_cast<const bf16x8*>(&vT[c2 * 16 + cl][kk * 32 + g * 8]);
#pragma unroll
    for (int rt = 0; rt < 2; rt++) {
      const bf16x8 pf = *reinterpret_cast<const bf16x8*>(&pL[w * 32 + rt * 16 + cl][kk * 32 + g * 8]);
#pragma unroll
      for (int c2 = 0; c2 < 4; c2++)
        cacc[rt][c2] = __builtin_amdgcn_mfma_f32_16x16x32_bf16(pf, vf[c2], cacc[rt][c2], 0, 0, 0);
    }
  }

  // epilogue: add CLS rank-1 term, store bf16 ctx
#pragma unroll
  for (int rt = 0; rt < 2; rt++)
#pragma unroll
    for (int c2 = 0; c2 < 4; c2++)
#pragma unroll
      for (int jj = 0; jj < 4; jj++) {
        const int row = w * 32 + rt * 16 + g * 4 + jj;
        const int kd = c2 * 16 + cl;
        const float val = cacc[rt][c2][jj] + pclsn[row] * vcls[kd];
        ctx[(rowbase + row) * HK_ + headoff + kd] = (bf16_t)val;
      }
}

// ---------------------------------------------------------------------------
extern "C" void kernel_launch(void* const* d_in, const int* in_sizes, int n_in,
                              void* d_out, int out_size, void* d_ws, size_t ws_size,
                              hipStream_t stream) {
  const float* Xq = (const float*)d_in[0];
  const float* Xkv = (const float*)d_in[1];
  const float* Wq = (const float*)d_in[2];
  const float* Wk = (const float*)d_in[3];
  const float* Wv = (const float*)d_in[4];
  const float* Wo = (const float*)d_in[5];
  float* out = (float*)d_out;

  char* ws = (char*)d_ws;
  bf16_t* wT = (bf16_t*)ws;                                   // 4 x 512 x 512 bf16
  size_t off = (size_t)4 * 512 * 512 * sizeof(bf16_t);        // 2 MiB
  bf16_t* xqb  = (bf16_t*)(ws + off); off += (size_t)M_ * D_ * 2;
  bf16_t* xkvb = (bf16_t*)(ws + off); off += (size_t)M_ * D_ * 2;
  bf16_t* qb = (bf16_t*)(ws + off); off += (size_t)M_ * HK_ * 2;
  bf16_t* kb = (bf16_t*)(ws + off); off += (size_t)M_ * HK_ * 2;
  bf16_t* vb = (bf16_t*)(ws + off);
  bf16_t* ctxb = xqb;  // xqb dead after Q-projection; reuse for ctx

  bf16_t* wTq = wT;
  bf16_t* wTk = wT + (size_t)512 * 512;  // wTk,wTv contiguous (1024 rows)
  bf16_t* wTo = wT + (size_t)3 * 512 * 512;

  prep_weights_kernel<<<dim3(512, 4), 128, 0, stream>>>(Wq, Wk, Wv, Wo, wT);
  cvt_x_kernel<<<dim3(M_ * D_ / 8 / 256, 2), 256, 0, stream>>>(Xq, Xkv, xqb, xkvb);

  // Q projection (scale folded into wTq)
  gemm_bt16<bf16_t><<<dim3(4, M_ / 128), 256, 0, stream>>>(xqb, wTq, qb, qb, HK_);
  // K+V projections fused: BT has 1024 rows
  gemm_bt16<bf16_t><<<dim3(8, M_ / 128), 256, 0, stream>>>(xkvb, wTk, kb, vb, HK_);

  attn_kernel<<<dim3(H_, C_, B_), 256, 0, stream>>>(qb, kb, vb, ctxb);

  // Output projection: ctx [M][512] bf16 @ WoT -> out fp32
  gemm_bt16<float><<<dim3(4, M_ / 128), 256, 0, stream>>>(ctxb, wTo, out, out, D_);
}

// Round 3
// 386.862 us; speedup vs baseline: 1.3962x; 1.0908x over previous
//
#include <hip/hip_runtime.h>
#include <hip/hip_bf16.h>
#include <type_traits>

#define B_ 8
#define L_ 8192
#define D_ 512
#define H_ 8
#define KD_ 64
#define W_ 128
#define C_ 64
#define M_ (B_ * L_)   // 65536
#define HK_ 512

typedef __bf16 bf16_t;
typedef __bf16 bf16x8 __attribute__((ext_vector_type(8)));
typedef float f32x4 __attribute__((ext_vector_type(4)));

#define GLOAD16(gp, lp)                                                        \
  __builtin_amdgcn_global_load_lds(                                            \
      (const __attribute__((address_space(1))) unsigned int*)(gp),             \
      (__attribute__((address_space(3))) unsigned int*)(lp), 16, 0, 0)

// ---------------------------------------------------------------------------
// Prep: wt[mat][n][d] = W[mat][d][n]  (bf16, transposed, q-scale folded)
// ---------------------------------------------------------------------------
__global__ void prep_weights_kernel(const float* __restrict__ Wq,
                                    const float* __restrict__ Wk,
                                    const float* __restrict__ Wv,
                                    const float* __restrict__ Wo,
                                    bf16_t* __restrict__ wt) {
  const int n = blockIdx.x;    // 0..511 (output row of W^T)
  const int mat = blockIdx.y;  // 0..3
  const float* src = (mat == 0) ? Wq : (mat == 1) ? Wk : (mat == 2) ? Wv : Wo;
  const float scale = (mat == 0) ? 0.125f : 1.0f;  // 1/sqrt(64) folded into Wq
  bf16_t* dst = wt + ((size_t)mat * 512 + n) * 512;
  for (int d = threadIdx.x; d < 512; d += blockDim.x) {
    dst[d] = (bf16_t)(src[(size_t)d * 512 + n] * scale);
  }
}

// ---------------------------------------------------------------------------
// Convert Xq / Xkv fp32 -> bf16 (streaming, vectorized 8 elem/thread)
// ---------------------------------------------------------------------------
__global__ void cvt_x_kernel(const float* __restrict__ xq,
                             const float* __restrict__ xkv,
                             bf16_t* __restrict__ oq,
                             bf16_t* __restrict__ okv) {
  const float* src = blockIdx.y ? xkv : xq;
  bf16_t* dst = blockIdx.y ? okv : oq;
  const size_t e = ((size_t)blockIdx.x * blockDim.x + threadIdx.x) * 8;
  float4 a = *reinterpret_cast<const float4*>(src + e);
  float4 b = *reinterpret_cast<const float4*>(src + e + 4);
  bf16x8 o;
  o[0] = (bf16_t)a.x; o[1] = (bf16_t)a.y; o[2] = (bf16_t)a.z; o[3] = (bf16_t)a.w;
  o[4] = (bf16_t)b.x; o[5] = (bf16_t)b.y; o[6] = (bf16_t)b.z; o[7] = (bf16_t)b.w;
  *reinterpret_cast<bf16x8*>(dst + e) = o;
}

// ---------------------------------------------------------------------------
// GEMM (m97 structure + XCD swizzle): C[m][n] = sum_k A[m][k] * BT[n][k].
//   1D grid of NX * (M/128) blocks, XCD-swizzled so all NX n-blocks of one
//   A-panel land on the same XCD (T1). NX/4 output segments of 4 n-blocks:
//   seg 0 reads A0 -> C0, segs 1,2 read A1 -> C1/C2 (fused QKV). All output
//   matrices are 512 cols wide. Kdim = 512.
// ---------------------------------------------------------------------------
template <typename OT, int NX>
__global__ __launch_bounds__(256, 3)
void gemm_bt16(const bf16_t* __restrict__ A0, const bf16_t* __restrict__ A1,
               const bf16_t* __restrict__ BT,
               OT* __restrict__ C0, OT* __restrict__ C1, OT* __restrict__ C2) {
  __shared__ bf16_t sA[128 * 64];
  __shared__ bf16_t sB[128 * 64];

  const int nb = gridDim.x;          // multiple of 8
  const int chunk = nb >> 3;
  const int bid = blockIdx.x;
  const int swz = (bid & 7) * chunk + (bid >> 3);  // bijective: nb % 8 == 0
  const int my = swz / NX;
  const int mx = swz - my * NX;
  const int m0 = my * 128;
  const int seg = mx >> 2;           // 0=Q, 1=K, 2=V (NX=12); always 0 (NX=4)
  const int n0o = (mx & 3) * 128;    // col offset within output matrix
  const int nB0 = mx * 128;          // row offset within BT

  const bf16_t* const A = (seg == 0) ? A0 : A1;
  OT* const outp = (seg == 0) ? C0 : (seg == 1) ? C1 : C2;

  const int tid = threadIdx.x;
  const int lane = tid & 63;
  const int w = tid >> 6;
  const int wr = (w >> 1) * 64;
  const int wc = (w & 1) * 64;

  const int srow = tid >> 3;       // staging row within a 32-row issue
  const int scol = (tid & 7) * 8;  // bf16 col (16B per lane)
  const int cl = lane & 15;
  const int g = lane >> 4;
  const int Kdim = 512;

  f32x4 acc[4][4] = {};

  for (int k0 = 0; k0 < Kdim; k0 += 64) {
    // ---- async stage A and B tiles [128][64] via global_load_lds x16B ----
#pragma unroll
    for (int i = 0; i < 4; i++) {
      const bf16_t* gp = A + (size_t)(m0 + i * 32 + srow) * Kdim + k0 + scol;
      char* lp = (char*)sA + i * 4096 + w * 1024;  // wave-uniform dest
      GLOAD16(gp, lp);
    }
#pragma unroll
    for (int i = 0; i < 4; i++) {
      const bf16_t* gp = BT + (size_t)(nB0 + i * 32 + srow) * Kdim + k0 + scol;
      char* lp = (char*)sB + i * 4096 + w * 1024;
      GLOAD16(gp, lp);
    }
    __syncthreads();  // vmcnt(0) drain + barrier

#pragma unroll
    for (int kk = 0; kk < 2; kk++) {
      bf16x8 afr[4], bfr[4];
#pragma unroll
      for (int t = 0; t < 4; t++)
        afr[t] = *reinterpret_cast<const bf16x8*>(
            &sA[(wr + t * 16 + cl) * 64 + kk * 32 + g * 8]);
#pragma unroll
      for (int t = 0; t < 4; t++)
        bfr[t] = *reinterpret_cast<const bf16x8*>(
            &sB[(wc + t * 16 + cl) * 64 + kk * 32 + g * 8]);
#pragma unroll
      for (int i = 0; i < 4; i++)
#pragma unroll
        for (int j = 0; j < 4; j++)
          acc[i][j] = __builtin_amdgcn_mfma_f32_16x16x32_bf16(afr[i], bfr[j],
                                                              acc[i][j], 0, 0, 0);
    }
    __syncthreads();
  }

  // ---- epilogue: C/D layout col=lane&15, row=(lane>>4)*4+jj ----
  const int crow = (lane >> 4) * 4;
  const int ccol = lane & 15;
#pragma unroll
  for (int i = 0; i < 4; i++) {
#pragma unroll
    for (int j = 0; j < 4; j++) {
      const int gm = m0 + wr + i * 16 + crow;
      const int gn = n0o + wc + j * 16 + ccol;
#pragma unroll
      for (int jj = 0; jj < 4; jj++) {
        const float vv = acc[i][j][jj];
        if constexpr (std::is_same<OT, float>::value)
          outp[(size_t)(gm + jj) * 512 + gn] = vv;
        else
          outp[(size_t)(gm + jj) * 512 + gn] = (bf16_t)vv;
      }
    }
  }
}

// ---------------------------------------------------------------------------
// Attention: one block per (h, c, b), XCD-swizzled so the 8 heads of one
// (c,b) chunk (sharing K/V rows) land on the same XCD. 4 waves x 32 rows.
// 128 chunk keys via MFMA + CLS key as VALU dot + rank-1 epilogue.
// ---------------------------------------------------------------------------
__global__ __launch_bounds__(256, 3)
void attn_kernel(const bf16_t* __restrict__ q, const bf16_t* __restrict__ k,
                 const bf16_t* __restrict__ v, bf16_t* __restrict__ ctx) {
  const int bid = blockIdx.x;                      // 4096 blocks
  const int swz = (bid & 7) * 512 + (bid >> 3);    // 4096 % 8 == 0
  const int h = swz & 7;
  const int cb = swz >> 3;
  const int c = cb & 63;
  const int b = cb >> 6;

  const int tid = threadIdx.x;
  const int lane = tid & 63;
  const int w = tid >> 6;
  const int cl = lane & 15;
  const int g = lane >> 4;

  __shared__ bf16_t vT[64][136];    // V^T: [kdim][m]
  __shared__ bf16_t pL[128][136];   // normalized P (bf16)
  __shared__ float scl[128];        // cls score, then normalized cls prob
  __shared__ bf16_t kcls[64];
  __shared__ bf16_t vcls[64];

  const size_t headoff = (size_t)h * KD_;
  const size_t rowbase = (size_t)b * L_ + (size_t)c * W_;

  // stage cls K/V (global position 0 of this batch)
  if (tid < 64) {
    kcls[tid] = k[(size_t)b * L_ * HK_ + headoff + tid];
    vcls[tid] = v[(size_t)b * L_ * HK_ + headoff + tid];
  }
  // stage V^T
  {
    const int m = tid >> 1;
    const int kd0 = (tid & 1) * 32;
    const bf16_t* vp = v + (rowbase + m) * HK_ + headoff + kd0;
#pragma unroll
    for (int i = 0; i < 4; i++) {
      bf16x8 t8 = *reinterpret_cast<const bf16x8*>(vp + i * 8);
#pragma unroll
      for (int j = 0; j < 8; j++) vT[kd0 + i * 8 + j][m] = t8[j];
    }
  }

  // Q fragments (direct from global)
  bf16x8 qf[2][2];
#pragma unroll
  for (int rt = 0; rt < 2; rt++)
#pragma unroll
    for (int kk = 0; kk < 2; kk++) {
      const size_t row = rowbase + w * 32 + rt * 16 + cl;
      qf[rt][kk] = *reinterpret_cast<const bf16x8*>(&q[row * HK_ + headoff + kk * 32 + g * 8]);
    }

  // QK^T: scores[128 rows x 128 chunk keys], this wave: rows w*32..+32
  f32x4 sacc[2][8] = {};
#pragma unroll
  for (int ct = 0; ct < 8; ct++) {
    bf16x8 kf[2];
#pragma unroll
    for (int kk = 0; kk < 2; kk++) {
      const size_t rowm = rowbase + ct * 16 + cl;
      kf[kk] = *reinterpret_cast<const bf16x8*>(&k[rowm * HK_ + headoff + kk * 32 + g * 8]);
    }
#pragma unroll
    for (int rt = 0; rt < 2; rt++)
#pragma unroll
      for (int kk = 0; kk < 2; kk++)
        sacc[rt][ct] = __builtin_amdgcn_mfma_f32_16x16x32_bf16(qf[rt][kk], kf[kk], sacc[rt][ct], 0, 0, 0);
  }

  __syncthreads();  // kcls/vcls/vT staged

  // CLS scores (VALU): row = w*32 + rt*16 + cl  (intra-wave only)
#pragma unroll
  for (int rt = 0; rt < 2; rt++) {
    float part = 0.f;
#pragma unroll
    for (int kk = 0; kk < 2; kk++)
#pragma unroll
      for (int j = 0; j < 8; j++)
        part += (float)qf[rt][kk][j] * (float)kcls[kk * 32 + g * 8 + j];
    part += __shfl_xor(part, 16);
    part += __shfl_xor(part, 32);
    if (g == 0) scl[w * 32 + rt * 16 + cl] = part;
  }

  // softmax (row = w*32 + rt*16 + g*4 + jj; cols: 16 cl-lanes x 8 in-lane ct)
  float invd[2][4];
#pragma unroll
  for (int rt = 0; rt < 2; rt++) {
#pragma unroll
    for (int jj = 0; jj < 4; jj++) {
      float mx = sacc[rt][0][jj];
#pragma unroll
      for (int ct = 1; ct < 8; ct++) mx = fmaxf(mx, sacc[rt][ct][jj]);
#pragma unroll
      for (int d = 1; d < 16; d <<= 1) mx = fmaxf(mx, __shfl_xor(mx, d));
      const float sc = scl[w * 32 + rt * 16 + g * 4 + jj];
      mx = fmaxf(mx, sc);
      float sum = 0.f;
#pragma unroll
      for (int ct = 0; ct < 8; ct++) {
        const float e = __expf(sacc[rt][ct][jj] - mx);
        sacc[rt][ct][jj] = e;
        sum += e;
      }
#pragma unroll
      for (int d = 1; d < 16; d <<= 1) sum += __shfl_xor(sum, d);
      const float pc = __expf(sc - mx);
      sum += pc;
      const float inv = 1.0f / sum;
      invd[rt][jj] = inv;
      // overwrite scl with normalized cls prob (same wave owns these rows;
      // every lane already read scl[row] above in this iteration)
      if (cl == 0) scl[w * 32 + rt * 16 + g * 4 + jj] = pc * inv;
    }
  }

  // write normalized P (bf16) for PV MFMA A-operand
#pragma unroll
  for (int rt = 0; rt < 2; rt++)
#pragma unroll
    for (int jj = 0; jj < 4; jj++) {
      const int row = w * 32 + rt * 16 + g * 4 + jj;
#pragma unroll
      for (int ct = 0; ct < 8; ct++)
        pL[row][ct * 16 + cl] = (bf16_t)(sacc[rt][ct][jj] * invd[rt][jj]);
    }
  __syncthreads();

  // PV: ctx[128 x 64] = P[128 x 128] @ V[128 x 64]
  f32x4 cacc[2][4] = {};
#pragma unroll
  for (int kk = 0; kk < 4; kk++) {  // m-dimension, 4 x 32
    bf16x8 vf[4];
#pragma unroll
    for (int c2 = 0; c2 < 4; c2++)
      vf[c2] = *reinterpret_cast<const bf16x8*>(&vT[c2 * 16 + cl][kk * 32 + g * 8]);
#pragma unroll
    for (int rt = 0; rt < 2; rt++) {
      const bf16x8 pf = *reinterpret_cast<const bf16x8*>(&pL[w * 32 + rt * 16 + cl][kk * 32 + g * 8]);
#pragma unroll
      for (int c2 = 0; c2 < 4; c2++)
        cacc[rt][c2] = __builtin_amdgcn_mfma_f32_16x16x32_bf16(pf, vf[c2], cacc[rt][c2], 0, 0, 0);
    }
  }

  // epilogue: add CLS rank-1 term, store bf16 ctx
#pragma unroll
  for (int rt = 0; rt < 2; rt++)
#pragma unroll
    for (int c2 = 0; c2 < 4; c2++)
#pragma unroll
      for (int jj = 0; jj < 4; jj++) {
        const int row = w * 32 + rt * 16 + g * 4 + jj;
        const int kd = c2 * 16 + cl;
        const float val = cacc[rt][c2][jj] + scl[row] * (float)vcls[kd];
        ctx[(rowbase + row) * HK_ + headoff + kd] = (bf16_t)val;
      }
}

// ---------------------------------------------------------------------------
extern "C" void kernel_launch(void* const* d_in, const int* in_sizes, int n_in,
                              void* d_out, int out_size, void* d_ws, size_t ws_size,
                              hipStream_t stream) {
  const float* Xq = (const float*)d_in[0];
  const float* Xkv = (const float*)d_in[1];
  const float* Wq = (const float*)d_in[2];
  const float* Wk = (const float*)d_in[3];
  const float* Wv = (const float*)d_in[4];
  const float* Wo = (const float*)d_in[5];
  float* out = (float*)d_out;

  char* ws = (char*)d_ws;
  bf16_t* wT = (bf16_t*)ws;                                   // 4 x 512 x 512 bf16
  size_t off = (size_t)4 * 512 * 512 * sizeof(bf16_t);        // 2 MiB
  bf16_t* xqb  = (bf16_t*)(ws + off); off += (size_t)M_ * D_ * 2;
  bf16_t* xkvb = (bf16_t*)(ws + off); off += (size_t)M_ * D_ * 2;
  bf16_t* qb = (bf16_t*)(ws + off); off += (size_t)M_ * HK_ * 2;
  bf16_t* kb = (bf16_t*)(ws + off); off += (size_t)M_ * HK_ * 2;
  bf16_t* vb = (bf16_t*)(ws + off);
  bf16_t* ctxb = xqb;  // xqb dead after QKV projection; reuse for ctx

  bf16_t* wTqkv = wT;                      // q|k|v stacked: 1536 rows
  bf16_t* wTo = wT + (size_t)3 * 512 * 512;

  prep_weights_kernel<<<dim3(512, 4), 128, 0, stream>>>(Wq, Wk, Wv, Wo, wT);
  cvt_x_kernel<<<dim3(M_ * D_ / 8 / 256, 2), 256, 0, stream>>>(Xq, Xkv, xqb, xkvb);

  // Fused Q+K+V projections: 12 n-blocks (4 per output) x 512 m-panels
  gemm_bt16<bf16_t, 12><<<dim3(12 * (M_ / 128)), 256, 0, stream>>>(
      xqb, xkvb, wTqkv, qb, kb, vb);

  attn_kernel<<<dim3(H_ * C_ * B_), 256, 0, stream>>>(qb, kb, vb, ctxb);

  // Output projection: ctx [M][512] bf16 @ WoT -> out fp32
  gemm_bt16<float, 4><<<dim3(4 * (M_ / 128)), 256, 0, stream>>>(
      ctxb, ctxb, wTo, out, out, out);
}

// Round 4
// 383.526 us; speedup vs baseline: 1.4083x; 1.0087x over previous
//
#include <hip/hip_runtime.h>
#include <hip/hip_bf16.h>
#include <type_traits>

#define B_ 8
#define L_ 8192
#define D_ 512
#define H_ 8
#define KD_ 64
#define W_ 128
#define C_ 64
#define M_ (B_ * L_)   // 65536
#define HK_ 512

typedef __bf16 bf16_t;
typedef __bf16 bf16x8 __attribute__((ext_vector_type(8)));
typedef float f32x4 __attribute__((ext_vector_type(4)));

#define GLOAD16(gp, lp)                                                        \
  __builtin_amdgcn_global_load_lds(                                            \
      (const __attribute__((address_space(1))) unsigned int*)(gp),             \
      (__attribute__((address_space(3))) unsigned int*)(lp), 16, 0, 0)

// ---------------------------------------------------------------------------
// Prep: wt[mat][n][d] = W[mat][d][n]  (bf16, transposed, q-scale folded)
// ---------------------------------------------------------------------------
__global__ void prep_weights_kernel(const float* __restrict__ Wq,
                                    const float* __restrict__ Wk,
                                    const float* __restrict__ Wv,
                                    const float* __restrict__ Wo,
                                    bf16_t* __restrict__ wt) {
  const int n = blockIdx.x;    // 0..511 (output row of W^T)
  const int mat = blockIdx.y;  // 0..3
  const float* src = (mat == 0) ? Wq : (mat == 1) ? Wk : (mat == 2) ? Wv : Wo;
  const float scale = (mat == 0) ? 0.125f : 1.0f;  // 1/sqrt(64) folded into Wq
  bf16_t* dst = wt + ((size_t)mat * 512 + n) * 512;
  for (int d = threadIdx.x; d < 512; d += blockDim.x) {
    dst[d] = (bf16_t)(src[(size_t)d * 512 + n] * scale);
  }
}

// ---------------------------------------------------------------------------
// Convert Xq / Xkv fp32 -> bf16 (streaming, vectorized 8 elem/thread)
// ---------------------------------------------------------------------------
__global__ void cvt_x_kernel(const float* __restrict__ xq,
                             const float* __restrict__ xkv,
                             bf16_t* __restrict__ oq,
                             bf16_t* __restrict__ okv) {
  const float* src = blockIdx.y ? xkv : xq;
  bf16_t* dst = blockIdx.y ? okv : oq;
  const size_t e = ((size_t)blockIdx.x * blockDim.x + threadIdx.x) * 8;
  float4 a = *reinterpret_cast<const float4*>(src + e);
  float4 b = *reinterpret_cast<const float4*>(src + e + 4);
  bf16x8 o;
  o[0] = (bf16_t)a.x; o[1] = (bf16_t)a.y; o[2] = (bf16_t)a.z; o[3] = (bf16_t)a.w;
  o[4] = (bf16_t)b.x; o[5] = (bf16_t)b.y; o[6] = (bf16_t)b.z; o[7] = (bf16_t)b.w;
  *reinterpret_cast<bf16x8*>(dst + e) = o;
}

// ---------------------------------------------------------------------------
// GEMM: C[m][n] = sum_k A[m][k] * BT[n][k].  Pipelined m97-successor:
//   BM=BN=128, BK=64, 4 waves (2x2 of 64x64), double-buffered LDS (64KB),
//   counted vmcnt(8) (loads for tile t+2 fly during tiles t..t+1's MFMA,
//   never drained in-loop), raw s_barrier, T2 16B-slot XOR swizzle applied
//   as pre-swizzled global source (linear gload_lds dest) + swizzled
//   ds_read, setprio around MFMA, XCD-swizzled 1D grid (T1).
//   NX n-blocks per A-panel: seg 0 reads A0 -> C0, segs 1,2 read A1 -> C1/C2
//   (fused QKV). All outputs 512 cols. Kdim = 512 (8 K-tiles).
// ---------------------------------------------------------------------------
template <typename OT, int NX>
__global__ __launch_bounds__(256, 2)
void gemm_bt16(const bf16_t* __restrict__ A0, const bf16_t* __restrict__ A1,
               const bf16_t* __restrict__ BT,
               OT* __restrict__ C0, OT* __restrict__ C1, OT* __restrict__ C2) {
  __shared__ bf16_t sA[2][128 * 64];
  __shared__ bf16_t sB[2][128 * 64];

  const int bid = blockIdx.x;
  const int swz = (bid & 7) * (NX * 64) + (bid >> 3);  // bijective: nb%8==0
  const int my = swz / NX;
  const int mx = swz - my * NX;
  const int m0 = my * 128;
  const int seg = mx >> 2;           // 0=Q, 1=K, 2=V (NX=12); always 0 (NX=4)
  const int n0o = (mx & 3) * 128;    // col offset within output matrix
  const int nB0 = mx * 128;          // row offset within BT

  const bf16_t* const A = (seg == 0) ? A0 : A1;
  OT* const outp = (seg == 0) ? C0 : (seg == 1) ? C1 : C2;

  const int tid = threadIdx.x;
  const int lane = tid & 63;
  const int w = tid >> 6;
  const int wr = (w >> 1) * 64;
  const int wc = (w & 1) * 64;
  const int cl = lane & 15;
  const int g = lane >> 4;
  const int c7 = cl & 7;

  // Staging geometry: wave w, issue i covers LDS rows i*32 + w*8 .. +8,
  // linear dest (lane*16B). Global source column is PRE-SWIZZLED so that
  // LDS[row][slot16] holds global[row][slot16 ^ (row&7)]  (rule #21).
  const int srow = lane >> 3;                       // 0..7 within 8-row group
  const int scol = ((lane & 7) ^ srow) * 8;         // swizzled col (elements)
  const bf16_t* const Ab = A + (size_t)(m0 + w * 8 + srow) * 512 + scol;
  const bf16_t* const Bb = BT + (size_t)(nB0 + w * 8 + srow) * 512 + scol;

  auto STAGE = [&](int t, int p) {  // 8 gload_lds per wave per K-tile
    const bf16_t* a = Ab + t * 64;
    const bf16_t* b = Bb + t * 64;
    char* la = (char*)&sA[p][0] + w * 1024;
    char* lb = (char*)&sB[p][0] + w * 1024;
#pragma unroll
    for (int i = 0; i < 4; i++) GLOAD16(a + (size_t)i * 32 * 512, la + i * 4096);
#pragma unroll
    for (int i = 0; i < 4; i++) GLOAD16(b + (size_t)i * 32 * 512, lb + i * 4096);
  };

  f32x4 acc[4][4] = {};

  auto BODY = [&](int t, int p, bool stage_next) __attribute__((always_inline)) {
    // ds_read all fragments of tile t from buf[p] (swizzled slot)
    bf16x8 afr[2][4], bfr[2][4];
#pragma unroll
    for (int kk = 0; kk < 2; kk++) {
#pragma unroll
      for (int tt = 0; tt < 4; tt++) {
        afr[kk][tt] = *reinterpret_cast<const bf16x8*>(
            &sA[p][(wr + tt * 16 + cl) * 64 + (((kk * 4 + g) ^ c7)) * 8]);
        bfr[kk][tt] = *reinterpret_cast<const bf16x8*>(
            &sB[p][(wc + tt * 16 + cl) * 64 + (((kk * 4 + g) ^ c7)) * 8]);
      }
    }
    asm volatile("s_waitcnt lgkmcnt(0)" ::: "memory");
    __builtin_amdgcn_s_barrier();           // all waves done reading buf[p]
    asm volatile("" ::: "memory");
    if (stage_next) STAGE(t + 2, p);        // overwrite consumed buffer
    __builtin_amdgcn_s_setprio(1);
#pragma unroll
    for (int kk = 0; kk < 2; kk++)
#pragma unroll
      for (int i = 0; i < 4; i++)
#pragma unroll
        for (int j = 0; j < 4; j++)
          acc[i][j] = __builtin_amdgcn_mfma_f32_16x16x32_bf16(
              afr[kk][i], bfr[kk][j], acc[i][j], 0, 0, 0);
    __builtin_amdgcn_s_setprio(0);
  };

  // prologue: two tiles in flight
  STAGE(0, 0);
  STAGE(1, 1);
  // steady state: at iter top, outstanding = tiles t (8) + t+1 (8);
  // vmcnt(8) -> tile t's loads landed, tile t+1's stay in flight.
  for (int t = 0; t < 6; ++t) {
    asm volatile("s_waitcnt vmcnt(8)" ::: "memory");
    __builtin_amdgcn_s_barrier();
    asm volatile("" ::: "memory");
    BODY(t, t & 1, true);
  }
  {  // t=6: outstanding = t6+t7 -> vmcnt(8); no further staging
    asm volatile("s_waitcnt vmcnt(8)" ::: "memory");
    __builtin_amdgcn_s_barrier();
    asm volatile("" ::: "memory");
    BODY(6, 0, false);
  }
  {  // t=7: only t7's 8 outstanding -> full drain
    asm volatile("s_waitcnt vmcnt(0)" ::: "memory");
    __builtin_amdgcn_s_barrier();
    asm volatile("" ::: "memory");
    BODY(7, 1, false);
  }

  // ---- epilogue: C/D layout col=lane&15, row=(lane>>4)*4+jj ----
  const int crow = (lane >> 4) * 4;
  const int ccol = lane & 15;
#pragma unroll
  for (int i = 0; i < 4; i++) {
#pragma unroll
    for (int j = 0; j < 4; j++) {
      const int gm = m0 + wr + i * 16 + crow;
      const int gn = n0o + wc + j * 16 + ccol;
#pragma unroll
      for (int jj = 0; jj < 4; jj++) {
        const float vv = acc[i][j][jj];
        if constexpr (std::is_same<OT, float>::value)
          outp[(size_t)(gm + jj) * 512 + gn] = vv;
        else
          outp[(size_t)(gm + jj) * 512 + gn] = (bf16_t)vv;
      }
    }
  }
}

// ---------------------------------------------------------------------------
// Attention: one block per (h, c, b), XCD-swizzled so the 8 heads of one
// (c,b) chunk (sharing K/V rows) land on the same XCD. 4 waves x 32 rows.
// 128 chunk keys via MFMA + CLS key as VALU dot + rank-1 epilogue.
// ---------------------------------------------------------------------------
__global__ __launch_bounds__(256, 3)
void attn_kernel(const bf16_t* __restrict__ q, const bf16_t* __restrict__ k,
                 const bf16_t* __restrict__ v, bf16_t* __restrict__ ctx) {
  const int bid = blockIdx.x;                      // 4096 blocks
  const int swz = (bid & 7) * 512 + (bid >> 3);    // 4096 % 8 == 0
  const int h = swz & 7;
  const int cb = swz >> 3;
  const int c = cb & 63;
  const int b = cb >> 6;

  const int tid = threadIdx.x;
  const int lane = tid & 63;
  const int w = tid >> 6;
  const int cl = lane & 15;
  const int g = lane >> 4;

  __shared__ bf16_t vT[64][136];    // V^T: [kdim][m]
  __shared__ bf16_t pL[128][136];   // normalized P (bf16)
  __shared__ float scl[128];        // cls score, then normalized cls prob
  __shared__ bf16_t kcls[64];
  __shared__ bf16_t vcls[64];

  const size_t headoff = (size_t)h * KD_;
  const size_t rowbase = (size_t)b * L_ + (size_t)c * W_;

  // stage cls K/V (global position 0 of this batch)
  if (tid < 64) {
    kcls[tid] = k[(size_t)b * L_ * HK_ + headoff + tid];
    vcls[tid] = v[(size_t)b * L_ * HK_ + headoff + tid];
  }
  // stage V^T
  {
    const int m = tid >> 1;
    const int kd0 = (tid & 1) * 32;
    const bf16_t* vp = v + (rowbase + m) * HK_ + headoff + kd0;
#pragma unroll
    for (int i = 0; i < 4; i++) {
      bf16x8 t8 = *reinterpret_cast<const bf16x8*>(vp + i * 8);
#pragma unroll
      for (int j = 0; j < 8; j++) vT[kd0 + i * 8 + j][m] = t8[j];
    }
  }

  // Q fragments (direct from global)
  bf16x8 qf[2][2];
#pragma unroll
  for (int rt = 0; rt < 2; rt++)
#pragma unroll
    for (int kk = 0; kk < 2; kk++) {
      const size_t row = rowbase + w * 32 + rt * 16 + cl;
      qf[rt][kk] = *reinterpret_cast<const bf16x8*>(&q[row * HK_ + headoff + kk * 32 + g * 8]);
    }

  // QK^T: scores[128 rows x 128 chunk keys], this wave: rows w*32..+32
  f32x4 sacc[2][8] = {};
#pragma unroll
  for (int ct = 0; ct < 8; ct++) {
    bf16x8 kf[2];
#pragma unroll
    for (int kk = 0; kk < 2; kk++) {
      const size_t rowm = rowbase + ct * 16 + cl;
      kf[kk] = *reinterpret_cast<const bf16x8*>(&k[rowm * HK_ + headoff + kk * 32 + g * 8]);
    }
#pragma unroll
    for (int rt = 0; rt < 2; rt++)
#pragma unroll
      for (int kk = 0; kk < 2; kk++)
        sacc[rt][ct] = __builtin_amdgcn_mfma_f32_16x16x32_bf16(qf[rt][kk], kf[kk], sacc[rt][ct], 0, 0, 0);
  }

  __syncthreads();  // kcls/vcls/vT staged

  // CLS scores (VALU): row = w*32 + rt*16 + cl  (intra-wave only)
#pragma unroll
  for (int rt = 0; rt < 2; rt++) {
    float part = 0.f;
#pragma unroll
    for (int kk = 0; kk < 2; kk++)
#pragma unroll
      for (int j = 0; j < 8; j++)
        part += (float)qf[rt][kk][j] * (float)kcls[kk * 32 + g * 8 + j];
    part += __shfl_xor(part, 16);
    part += __shfl_xor(part, 32);
    if (g == 0) scl[w * 32 + rt * 16 + cl] = part;
  }

  // softmax (row = w*32 + rt*16 + g*4 + jj; cols: 16 cl-lanes x 8 in-lane ct)
  float invd[2][4];
#pragma unroll
  for (int rt = 0; rt < 2; rt++) {
#pragma unroll
    for (int jj = 0; jj < 4; jj++) {
      float mx = sacc[rt][0][jj];
#pragma unroll
      for (int ct = 1; ct < 8; ct++) mx = fmaxf(mx, sacc[rt][ct][jj]);
#pragma unroll
      for (int d = 1; d < 16; d <<= 1) mx = fmaxf(mx, __shfl_xor(mx, d));
      const float sc = scl[w * 32 + rt * 16 + g * 4 + jj];
      mx = fmaxf(mx, sc);
      float sum = 0.f;
#pragma unroll
      for (int ct = 0; ct < 8; ct++) {
        const float e = __expf(sacc[rt][ct][jj] - mx);
        sacc[rt][ct][jj] = e;
        sum += e;
      }
#pragma unroll
      for (int d = 1; d < 16; d <<= 1) sum += __shfl_xor(sum, d);
      const float pc = __expf(sc - mx);
      sum += pc;
      const float inv = 1.0f / sum;
      invd[rt][jj] = inv;
      // overwrite scl with normalized cls prob (same wave owns these rows;
      // every lane already read scl[row] above in this iteration)
      if (cl == 0) scl[w * 32 + rt * 16 + g * 4 + jj] = pc * inv;
    }
  }

  // write normalized P (bf16) for PV MFMA A-operand
#pragma unroll
  for (int rt = 0; rt < 2; rt++)
#pragma unroll
    for (int jj = 0; jj < 4; jj++) {
      const int row = w * 32 + rt * 16 + g * 4 + jj;
#pragma unroll
      for (int ct = 0; ct < 8; ct++)
        pL[row][ct * 16 + cl] = (bf16_t)(sacc[rt][ct][jj] * invd[rt][jj]);
    }
  __syncthreads();

  // PV: ctx[128 x 64] = P[128 x 128] @ V[128 x 64]
  f32x4 cacc[2][4] = {};
#pragma unroll
  for (int kk = 0; kk < 4; kk++) {  // m-dimension, 4 x 32
    bf16x8 vf[4];
#pragma unroll
    for (int c2 = 0; c2 < 4; c2++)
      vf[c2] = *reinterpret_cast<const bf16x8*>(&vT[c2 * 16 + cl][kk * 32 + g * 8]);
#pragma unroll
    for (int rt = 0; rt < 2; rt++) {
      const bf16x8 pf = *reinterpret_cast<const bf16x8*>(&pL[w * 32 + rt * 16 + cl][kk * 32 + g * 8]);
#pragma unroll
      for (int c2 = 0; c2 < 4; c2++)
        cacc[rt][c2] = __builtin_amdgcn_mfma_f32_16x16x32_bf16(pf, vf[c2], cacc[rt][c2], 0, 0, 0);
    }
  }

  // epilogue: add CLS rank-1 term, store bf16 ctx
#pragma unroll
  for (int rt = 0; rt < 2; rt++)
#pragma unroll
    for (int c2 = 0; c2 < 4; c2++)
#pragma unroll
      for (int jj = 0; jj < 4; jj++) {
        const int row = w * 32 + rt * 16 + g * 4 + jj;
        const int kd = c2 * 16 + cl;
        const float val = cacc[rt][c2][jj] + scl[row] * (float)vcls[kd];
        ctx[(rowbase + row) * HK_ + headoff + kd] = (bf16_t)val;
      }
}

// ---------------------------------------------------------------------------
extern "C" void kernel_launch(void* const* d_in, const int* in_sizes, int n_in,
                              void* d_out, int out_size, void* d_ws, size_t ws_size,
                              hipStream_t stream) {
  const float* Xq = (const float*)d_in[0];
  const float* Xkv = (const float*)d_in[1];
  const float* Wq = (const float*)d_in[2];
  const float* Wk = (const float*)d_in[3];
  const float* Wv = (const float*)d_in[4];
  const float* Wo = (const float*)d_in[5];
  float* out = (float*)d_out;

  char* ws = (char*)d_ws;
  bf16_t* wT = (bf16_t*)ws;                                   // 4 x 512 x 512 bf16
  size_t off = (size_t)4 * 512 * 512 * sizeof(bf16_t);        // 2 MiB
  bf16_t* xqb  = (bf16_t*)(ws + off); off += (size_t)M_ * D_ * 2;
  bf16_t* xkvb = (bf16_t*)(ws + off); off += (size_t)M_ * D_ * 2;
  bf16_t* qb = (bf16_t*)(ws + off); off += (size_t)M_ * HK_ * 2;
  bf16_t* kb = (bf16_t*)(ws + off); off += (size_t)M_ * HK_ * 2;
  bf16_t* vb = (bf16_t*)(ws + off);
  bf16_t* ctxb = xqb;  // xqb dead after QKV projection; reuse for ctx

  bf16_t* wTqkv = wT;                      // q|k|v stacked: 1536 rows
  bf16_t* wTo = wT + (size_t)3 * 512 * 512;

  prep_weights_kernel<<<dim3(512, 4), 128, 0, stream>>>(Wq, Wk, Wv, Wo, wT);
  cvt_x_kernel<<<dim3(M_ * D_ / 8 / 256, 2), 256, 0, stream>>>(Xq, Xkv, xqb, xkvb);

  // Fused Q+K+V projections: 12 n-blocks (4 per output) x 512 m-panels
  gemm_bt16<bf16_t, 12><<<dim3(12 * (M_ / 128)), 256, 0, stream>>>(
      xqb, xkvb, wTqkv, qb, kb, vb);

  attn_kernel<<<dim3(H_ * C_ * B_), 256, 0, stream>>>(qb, kb, vb, ctxb);

  // Output projection: ctx [M][512] bf16 @ WoT -> out fp32
  gemm_bt16<float, 4><<<dim3(4 * (M_ / 128)), 256, 0, stream>>>(
      ctxb, ctxb, wTo, out, out, out);
}

// Round 5
// 366.814 us; speedup vs baseline: 1.4725x; 1.0456x over previous
//
#include <hip/hip_runtime.h>
#include <hip/hip_bf16.h>
#include <type_traits>

#define B_ 8
#define L_ 8192
#define D_ 512
#define H_ 8
#define KD_ 64
#define W_ 128
#define C_ 64
#define M_ (B_ * L_)   // 65536
#define HK_ 512

typedef __bf16 bf16_t;
typedef __bf16 bf16x8 __attribute__((ext_vector_type(8)));
typedef float f32x4 __attribute__((ext_vector_type(4)));

#define GLOAD16(gp, lp)                                                        \
  __builtin_amdgcn_global_load_lds(                                            \
      (const __attribute__((address_space(1))) unsigned int*)(gp),             \
      (__attribute__((address_space(3))) unsigned int*)(lp), 16, 0, 0)

#define WAIT_LGKM0()                                                           \
  do {                                                                         \
    asm volatile("s_waitcnt lgkmcnt(0)" ::: "memory");                         \
    __builtin_amdgcn_sched_barrier(0);                                         \
  } while (0)

// ---------------------------------------------------------------------------
// Prep: wt[mat][n][d] = W[mat][d][n]  (bf16, transposed, q-scale folded)
// ---------------------------------------------------------------------------
__global__ void prep_weights_kernel(const float* __restrict__ Wq,
                                    const float* __restrict__ Wk,
                                    const float* __restrict__ Wv,
                                    const float* __restrict__ Wo,
                                    bf16_t* __restrict__ wt) {
  const int n = blockIdx.x;    // 0..511 (output row of W^T)
  const int mat = blockIdx.y;  // 0..3
  const float* src = (mat == 0) ? Wq : (mat == 1) ? Wk : (mat == 2) ? Wv : Wo;
  const float scale = (mat == 0) ? 0.125f : 1.0f;  // 1/sqrt(64) folded into Wq
  bf16_t* dst = wt + ((size_t)mat * 512 + n) * 512;
  for (int d = threadIdx.x; d < 512; d += blockDim.x) {
    dst[d] = (bf16_t)(src[(size_t)d * 512 + n] * scale);
  }
}

// ---------------------------------------------------------------------------
// Convert Xq / Xkv fp32 -> bf16 (streaming, vectorized 8 elem/thread)
// ---------------------------------------------------------------------------
__global__ void cvt_x_kernel(const float* __restrict__ xq,
                             const float* __restrict__ xkv,
                             bf16_t* __restrict__ oq,
                             bf16_t* __restrict__ okv) {
  const float* src = blockIdx.y ? xkv : xq;
  bf16_t* dst = blockIdx.y ? okv : oq;
  const size_t e = ((size_t)blockIdx.x * blockDim.x + threadIdx.x) * 8;
  float4 a = *reinterpret_cast<const float4*>(src + e);
  float4 b = *reinterpret_cast<const float4*>(src + e + 4);
  bf16x8 o;
  o[0] = (bf16_t)a.x; o[1] = (bf16_t)a.y; o[2] = (bf16_t)a.z; o[3] = (bf16_t)a.w;
  o[4] = (bf16_t)b.x; o[5] = (bf16_t)b.y; o[6] = (bf16_t)b.z; o[7] = (bf16_t)b.w;
  *reinterpret_cast<bf16x8*>(dst + e) = o;
}

// ---------------------------------------------------------------------------
// 256x256 8-phase GEMM (m201-template port): C[m][n] = sum_k A[m][k]*BT[n][k]
//   512 threads = 8 waves (2M x 4N), per-wave output 128x64, BK=64, K=512.
//   LDS 128 KB: [buf2][mat2][khalf2] regions of 16 KB (256 rows x 32 k).
//   Phase = {4-8 ds_read | stage 1 half-tile | bar | lgkm0 | 16 MFMA | bar}.
//   vmcnt(6) once per K-tile (3 half-tiles in flight), drained at tail.
//   XOR slot-swizzle (slot ^= row&3) both-sides: pre-swizzled global source
//   (linear gload_lds dest) + swizzled ds_read. T1 XCD-bijective grid.
//   NTILE n-tiles of 256; seg = mx>>1: 0 reads A0->C0, 1/2 read A1->C1/C2.
// ---------------------------------------------------------------------------
__device__ __forceinline__ bf16x8 rdfrag(const bf16_t* region, int rowbase,
                                         int lane) {
  const int fr = lane & 15;
  const int fs = (lane >> 4) ^ (lane & 3);  // swizzled 16B slot
  return *reinterpret_cast<const bf16x8*>(region + (rowbase + fr) * 32 + fs * 8);
}

template <typename OT, int NTILE>
__global__ __launch_bounds__(512, 2)
void gemm256(const bf16_t* __restrict__ A0, const bf16_t* __restrict__ A1,
             const bf16_t* __restrict__ BT,
             OT* __restrict__ C0, OT* __restrict__ C1, OT* __restrict__ C2) {
  __shared__ bf16_t lds[8 * 8192];  // 128 KiB: region(buf,mat,kh) = 16 KB

  constexpr int NB = NTILE * 256;  // grid size (multiple of 8)
  const int bid = blockIdx.x;
  const int swz = (bid & 7) * (NB / 8) + (bid >> 3);
  const int my = swz / NTILE;
  const int mx = swz - my * NTILE;
  const int m0 = my * 256;
  const int seg = mx >> 1;
  const int ncol0 = (mx & 1) * 256;
  const int nB0 = mx * 256;

  const bf16_t* const A = (seg == 0) ? A0 : A1;
  OT* const outp = (seg == 0) ? C0 : (seg == 1) ? C1 : C2;

  const int tid = threadIdx.x;
  const int lane = tid & 63;
  const int wid = tid >> 6;
  const int wmB = (wid >> 2) * 128;  // wave m-base (2 M-waves)
  const int wnB = (wid & 3) * 64;    // wave n-base (4 N-waves)

  // staging geometry: thread covers rows (tid>>2) and +128 of a half-tile,
  // 16B slot (tid&3); global slot pre-swizzled by row&3 (rule #21).
  const int sr0 = tid >> 2;
  const int sgs = (tid & 3) ^ (sr0 & 3);
  const bf16_t* const Agb = A + ((size_t)m0 + sr0) * 512 + sgs * 8;
  const bf16_t* const Bgb = BT + ((size_t)nB0 + sr0) * 512 + sgs * 8;

  auto stage = [&](int tile, int mat, int kh) {
    if (tile >= 8) return;
    bf16_t* reg = lds + (((tile & 1) * 4) + mat * 2 + kh) * 8192;
    const bf16_t* g0 = (mat == 0 ? Agb : Bgb) + tile * 64 + kh * 32;
    char* lp = (char*)reg + wid * 1024;  // wave-uniform dest
    GLOAD16(g0, lp);
    GLOAD16(g0 + (size_t)128 * 512, lp + 8192);
  };

  f32x4 acc[8][4] = {};
  bf16x8 a0[4], a1[4], a2[4], a3[4], b0[4], b2[4];

  // prologue: tile0 fully + tile1 {Bkh0, Akh0, Bkh1}  (7 half-tiles)
  stage(0, 0, 0); stage(0, 1, 0); stage(0, 0, 1); stage(0, 1, 1);
  stage(1, 1, 0); stage(1, 0, 0); stage(1, 1, 1);
  asm volatile("s_waitcnt vmcnt(6)" ::: "memory");  // tile0 landed
  __builtin_amdgcn_s_barrier();

  for (int t = 0; t < 8; ++t) {
    const int p = t & 1;
    const bf16_t* Ap0 = lds + (p * 4 + 0) * 8192;
    const bf16_t* Ap1 = lds + (p * 4 + 1) * 8192;
    const bf16_t* Bp0 = lds + (p * 4 + 2) * 8192;
    const bf16_t* Bp1 = lds + (p * 4 + 3) * 8192;

    // ---- ph0: RD A[kh0] m0-3 + B[kh0]; ST A(t+1)kh1; MFMA tail t-1 ----
#pragma unroll
    for (int q = 0; q < 4; q++) a0[q] = rdfrag(Ap0, wmB + q * 16, lane);
#pragma unroll
    for (int q = 0; q < 4; q++) b0[q] = rdfrag(Bp0, wnB + q * 16, lane);
    stage(t + 1, 0, 1);
    __builtin_amdgcn_s_barrier();
    WAIT_LGKM0();
    if (t > 0) {
      __builtin_amdgcn_s_setprio(1);
#pragma unroll
      for (int i = 0; i < 4; i++)
#pragma unroll
        for (int j = 0; j < 4; j++)
          acc[i + 4][j] = __builtin_amdgcn_mfma_f32_16x16x32_bf16(
              a3[i], b2[j], acc[i + 4][j], 0, 0, 0);
      __builtin_amdgcn_s_setprio(0);
    }
    __builtin_amdgcn_s_barrier();

    // ---- ph1: RD A[kh0] m4-7; ST B(t+2)kh0; MFMA m0-3 x kh0 ----
#pragma unroll
    for (int q = 0; q < 4; q++) a1[q] = rdfrag(Ap0, wmB + 64 + q * 16, lane);
    stage(t + 2, 1, 0);
    __builtin_amdgcn_s_barrier();
    WAIT_LGKM0();
    __builtin_amdgcn_s_setprio(1);
#pragma unroll
    for (int i = 0; i < 4; i++)
#pragma unroll
      for (int j = 0; j < 4; j++)
        acc[i][j] = __builtin_amdgcn_mfma_f32_16x16x32_bf16(a0[i], b0[j],
                                                            acc[i][j], 0, 0, 0);
    __builtin_amdgcn_s_setprio(0);
    __builtin_amdgcn_s_barrier();

    // ---- ph2: RD A[kh1] m0-3 + B[kh1]; ST A(t+2)kh0; MFMA m4-7 x kh0 ----
#pragma unroll
    for (int q = 0; q < 4; q++) a2[q] = rdfrag(Ap1, wmB + q * 16, lane);
#pragma unroll
    for (int q = 0; q < 4; q++) b2[q] = rdfrag(Bp1, wnB + q * 16, lane);
    stage(t + 2, 0, 0);
    __builtin_amdgcn_s_barrier();
    WAIT_LGKM0();
    __builtin_amdgcn_s_setprio(1);
#pragma unroll
    for (int i = 0; i < 4; i++)
#pragma unroll
      for (int j = 0; j < 4; j++)
        acc[i + 4][j] = __builtin_amdgcn_mfma_f32_16x16x32_bf16(
            a1[i], b0[j], acc[i + 4][j], 0, 0, 0);
    __builtin_amdgcn_s_setprio(0);
    __builtin_amdgcn_s_barrier();

    // ---- ph3: RD A[kh1] m4-7; ST B(t+2)kh1; MFMA m0-3 x kh1; gate ----
#pragma unroll
    for (int q = 0; q < 4; q++) a3[q] = rdfrag(Ap1, wmB + 64 + q * 16, lane);
    stage(t + 2, 1, 1);
    __builtin_amdgcn_s_barrier();
    WAIT_LGKM0();
    __builtin_amdgcn_s_setprio(1);
#pragma unroll
    for (int i = 0; i < 4; i++)
#pragma unroll
      for (int j = 0; j < 4; j++)
        acc[i][j] = __builtin_amdgcn_mfma_f32_16x16x32_bf16(a2[i], b2[j],
                                                            acc[i][j], 0, 0, 0);
    __builtin_amdgcn_s_setprio(0);
    if (t < 6) {
      asm volatile("s_waitcnt vmcnt(6)" ::: "memory");  // tile t+1 landed
    } else {
      asm volatile("s_waitcnt vmcnt(0)" ::: "memory");  // tail drain
    }
    __builtin_amdgcn_s_barrier();
  }

  // epilogue quadrant: tile7 m4-7 x kh1
#pragma unroll
  for (int i = 0; i < 4; i++)
#pragma unroll
    for (int j = 0; j < 4; j++)
      acc[i + 4][j] = __builtin_amdgcn_mfma_f32_16x16x32_bf16(
          a3[i], b2[j], acc[i + 4][j], 0, 0, 0);

  // ---- C-write: C/D layout col=lane&15, row=(lane>>4)*4+jj ----
  const int crow = (lane >> 4) * 4;
  const int ccol = lane & 15;
#pragma unroll
  for (int i = 0; i < 8; i++) {
#pragma unroll
    for (int j = 0; j < 4; j++) {
      const int gm = m0 + wmB + i * 16 + crow;
      const int gn = ncol0 + wnB + j * 16 + ccol;
#pragma unroll
      for (int jj = 0; jj < 4; jj++) {
        const float vv = acc[i][j][jj];
        if constexpr (std::is_same<OT, float>::value)
          outp[(size_t)(gm + jj) * 512 + gn] = vv;
        else
          outp[(size_t)(gm + jj) * 512 + gn] = (bf16_t)vv;
      }
    }
  }
}

// ---------------------------------------------------------------------------
// Attention: one block per (h, c, b), XCD-swizzled so the 8 heads of one
// (c,b) chunk (sharing K/V rows) land on the same XCD. 4 waves x 32 rows.
// 128 chunk keys via MFMA + CLS key as VALU dot + rank-1 epilogue.
// ---------------------------------------------------------------------------
__global__ __launch_bounds__(256, 3)
void attn_kernel(const bf16_t* __restrict__ q, const bf16_t* __restrict__ k,
                 const bf16_t* __restrict__ v, bf16_t* __restrict__ ctx) {
  const int bid = blockIdx.x;                      // 4096 blocks
  const int swz = (bid & 7) * 512 + (bid >> 3);    // 4096 % 8 == 0
  const int h = swz & 7;
  const int cb = swz >> 3;
  const int c = cb & 63;
  const int b = cb >> 6;

  const int tid = threadIdx.x;
  const int lane = tid & 63;
  const int w = tid >> 6;
  const int cl = lane & 15;
  const int g = lane >> 4;

  __shared__ bf16_t vT[64][136];    // V^T: [kdim][m]
  __shared__ bf16_t pL[128][136];   // normalized P (bf16)
  __shared__ float scl[128];        // cls score, then normalized cls prob
  __shared__ bf16_t kcls[64];
  __shared__ bf16_t vcls[64];

  const size_t headoff = (size_t)h * KD_;
  const size_t rowbase = (size_t)b * L_ + (size_t)c * W_;

  // stage cls K/V (global position 0 of this batch)
  if (tid < 64) {
    kcls[tid] = k[(size_t)b * L_ * HK_ + headoff + tid];
    vcls[tid] = v[(size_t)b * L_ * HK_ + headoff + tid];
  }
  // stage V^T
  {
    const int m = tid >> 1;
    const int kd0 = (tid & 1) * 32;
    const bf16_t* vp = v + (rowbase + m) * HK_ + headoff + kd0;
#pragma unroll
    for (int i = 0; i < 4; i++) {
      bf16x8 t8 = *reinterpret_cast<const bf16x8*>(vp + i * 8);
#pragma unroll
      for (int j = 0; j < 8; j++) vT[kd0 + i * 8 + j][m] = t8[j];
    }
  }

  // Q fragments (direct from global)
  bf16x8 qf[2][2];
#pragma unroll
  for (int rt = 0; rt < 2; rt++)
#pragma unroll
    for (int kk = 0; kk < 2; kk++) {
      const size_t row = rowbase + w * 32 + rt * 16 + cl;
      qf[rt][kk] = *reinterpret_cast<const bf16x8*>(&q[row * HK_ + headoff + kk * 32 + g * 8]);
    }

  // QK^T: scores[128 rows x 128 chunk keys], this wave: rows w*32..+32
  f32x4 sacc[2][8] = {};
#pragma unroll
  for (int ct = 0; ct < 8; ct++) {
    bf16x8 kf[2];
#pragma unroll
    for (int kk = 0; kk < 2; kk++) {
      const size_t rowm = rowbase + ct * 16 + cl;
      kf[kk] = *reinterpret_cast<const bf16x8*>(&k[rowm * HK_ + headoff + kk * 32 + g * 8]);
    }
#pragma unroll
    for (int rt = 0; rt < 2; rt++)
#pragma unroll
      for (int kk = 0; kk < 2; kk++)
        sacc[rt][ct] = __builtin_amdgcn_mfma_f32_16x16x32_bf16(qf[rt][kk], kf[kk], sacc[rt][ct], 0, 0, 0);
  }

  __syncthreads();  // kcls/vcls/vT staged

  // CLS scores (VALU): row = w*32 + rt*16 + cl  (intra-wave only)
#pragma unroll
  for (int rt = 0; rt < 2; rt++) {
    float part = 0.f;
#pragma unroll
    for (int kk = 0; kk < 2; kk++)
#pragma unroll
      for (int j = 0; j < 8; j++)
        part += (float)qf[rt][kk][j] * (float)kcls[kk * 32 + g * 8 + j];
    part += __shfl_xor(part, 16);
    part += __shfl_xor(part, 32);
    if (g == 0) scl[w * 32 + rt * 16 + cl] = part;
  }

  // softmax (row = w*32 + rt*16 + g*4 + jj; cols: 16 cl-lanes x 8 in-lane ct)
  float invd[2][4];
#pragma unroll
  for (int rt = 0; rt < 2; rt++) {
#pragma unroll
    for (int jj = 0; jj < 4; jj++) {
      float mx = sacc[rt][0][jj];
#pragma unroll
      for (int ct = 1; ct < 8; ct++) mx = fmaxf(mx, sacc[rt][ct][jj]);
#pragma unroll
      for (int d = 1; d < 16; d <<= 1) mx = fmaxf(mx, __shfl_xor(mx, d));
      const float sc = scl[w * 32 + rt * 16 + g * 4 + jj];
      mx = fmaxf(mx, sc);
      float sum = 0.f;
#pragma unroll
      for (int ct = 0; ct < 8; ct++) {
        const float e = __expf(sacc[rt][ct][jj] - mx);
        sacc[rt][ct][jj] = e;
        sum += e;
      }
#pragma unroll
      for (int d = 1; d < 16; d <<= 1) sum += __shfl_xor(sum, d);
      const float pc = __expf(sc - mx);
      sum += pc;
      const float inv = 1.0f / sum;
      invd[rt][jj] = inv;
      // overwrite scl with normalized cls prob (same wave owns these rows;
      // every lane already read scl[row] above in this iteration)
      if (cl == 0) scl[w * 32 + rt * 16 + g * 4 + jj] = pc * inv;
    }
  }

  // write normalized P (bf16) for PV MFMA A-operand
#pragma unroll
  for (int rt = 0; rt < 2; rt++)
#pragma unroll
    for (int jj = 0; jj < 4; jj++) {
      const int row = w * 32 + rt * 16 + g * 4 + jj;
#pragma unroll
      for (int ct = 0; ct < 8; ct++)
        pL[row][ct * 16 + cl] = (bf16_t)(sacc[rt][ct][jj] * invd[rt][jj]);
    }
  __syncthreads();

  // PV: ctx[128 x 64] = P[128 x 128] @ V[128 x 64]
  f32x4 cacc[2][4] = {};
#pragma unroll
  for (int kk = 0; kk < 4; kk++) {  // m-dimension, 4 x 32
    bf16x8 vf[4];
#pragma unroll
    for (int c2 = 0; c2 < 4; c2++)
      vf[c2] = *reinterpret_cast<const bf16x8*>(&vT[c2 * 16 + cl][kk * 32 + g * 8]);
#pragma unroll
    for (int rt = 0; rt < 2; rt++) {
      const bf16x8 pf = *reinterpret_cast<const bf16x8*>(&pL[w * 32 + rt * 16 + cl][kk * 32 + g * 8]);
#pragma unroll
      for (int c2 = 0; c2 < 4; c2++)
        cacc[rt][c2] = __builtin_amdgcn_mfma_f32_16x16x32_bf16(pf, vf[c2], cacc[rt][c2], 0, 0, 0);
    }
  }

  // epilogue: add CLS rank-1 term, store bf16 ctx
#pragma unroll
  for (int rt = 0; rt < 2; rt++)
#pragma unroll
    for (int c2 = 0; c2 < 4; c2++)
#pragma unroll
      for (int jj = 0; jj < 4; jj++) {
        const int row = w * 32 + rt * 16 + g * 4 + jj;
        const int kd = c2 * 16 + cl;
        const float val = cacc[rt][c2][jj] + scl[row] * (float)vcls[kd];
        ctx[(rowbase + row) * HK_ + headoff + kd] = (bf16_t)val;
      }
}

// ---------------------------------------------------------------------------
extern "C" void kernel_launch(void* const* d_in, const int* in_sizes, int n_in,
                              void* d_out, int out_size, void* d_ws, size_t ws_size,
                              hipStream_t stream) {
  const float* Xq = (const float*)d_in[0];
  const float* Xkv = (const float*)d_in[1];
  const float* Wq = (const float*)d_in[2];
  const float* Wk = (const float*)d_in[3];
  const float* Wv = (const float*)d_in[4];
  const float* Wo = (const float*)d_in[5];
  float* out = (float*)d_out;

  char* ws = (char*)d_ws;
  bf16_t* wT = (bf16_t*)ws;                                   // 4 x 512 x 512 bf16
  size_t off = (size_t)4 * 512 * 512 * sizeof(bf16_t);        // 2 MiB
  bf16_t* xqb  = (bf16_t*)(ws + off); off += (size_t)M_ * D_ * 2;
  bf16_t* xkvb = (bf16_t*)(ws + off); off += (size_t)M_ * D_ * 2;
  bf16_t* qb = (bf16_t*)(ws + off); off += (size_t)M_ * HK_ * 2;
  bf16_t* kb = (bf16_t*)(ws + off); off += (size_t)M_ * HK_ * 2;
  bf16_t* vb = (bf16_t*)(ws + off);
  bf16_t* ctxb = xqb;  // xqb dead after QKV projection; reuse for ctx

  bf16_t* wTqkv = wT;                      // q|k|v stacked: 1536 rows
  bf16_t* wTo = wT + (size_t)3 * 512 * 512;

  prep_weights_kernel<<<dim3(512, 4), 128, 0, stream>>>(Wq, Wk, Wv, Wo, wT);
  cvt_x_kernel<<<dim3(M_ * D_ / 8 / 256, 2), 256, 0, stream>>>(Xq, Xkv, xqb, xkvb);

  // Fused Q+K+V projections: 6 n-tiles (2 per output) x 256 m-panels
  gemm256<bf16_t, 6><<<dim3(6 * (M_ / 256)), 512, 0, stream>>>(
      xqb, xkvb, wTqkv, qb, kb, vb);

  attn_kernel<<<dim3(H_ * C_ * B_), 256, 0, stream>>>(qb, kb, vb, ctxb);

  // Output projection: ctx [M][512] bf16 @ WoT -> out fp32
  gemm256<float, 2><<<dim3(2 * (M_ / 256)), 512, 0, stream>>>(
      ctxb, ctxb, wTo, out, out, out);
}